// Round 1
// baseline (144.837 us; speedup 1.0000x reference)
//
#include <hip/hip_runtime.h>
#include <math.h>

#define B_TOT 2048
#define D_INC 15
#define KW    40
#define CCH   20
#define LP    31
#define SIGCH 8420
#define SIGP  8448   // padded K; 8448 = 11*768, 768 = 12*64
#define NOUT  128
#define KSPLIT 11
#define KLEN  768    // per-split K: 24 k-steps of 32

typedef _Float16 f16;
typedef _Float16 f16x8 __attribute__((ext_vector_type(8)));
typedef _Float16 f16x4 __attribute__((ext_vector_type(4)));
typedef _Float16 f16x2 __attribute__((ext_vector_type(2)));
typedef float    f32x4 __attribute__((ext_vector_type(4)));

// ---------------------------------------------------------------------------
// Kernel 0: prep. Block 0: conv weights -> MFMA A-fragment layout (fp16).
// Blocks 1..32: w_out -> f16 convert (moved out of k_augsig so it runs on
// the CUs that previously idled behind the 1-block prep).
// ---------------------------------------------------------------------------
__global__ __launch_bounds__(256) void k_prep(const float* __restrict__ w1,
                                              const float* __restrict__ w_out,
                                              f16* __restrict__ wA,
                                              f16* __restrict__ wh)
{
    if (blockIdx.x == 0) {
        const int ln = threadIdx.x & 63;
        const int wv = threadIdx.x >> 6;
        const int h  = ln & 15;
        const int q4 = ln >> 4;
        for (int gi = 0; gi < 5; ++gi) {
            int g = wv * 5 + gi;
            f16x8 v;
#pragma unroll
            for (int j = 0; j < 8; ++j) {
                int kq = q4 * 8 + j;
                int kk = 2 * g + (kq >> 4);
                int c  = kq & 15;
                v[j] = (c < D_INC) ? (f16)w1[h * 600 + c * 40 + kk] : (f16)0.f;
            }
            *(f16x8*)(wA + g * 512 + ln * 8) = v;
        }
        return;
    }
    int t0 = (blockIdx.x - 1) * 256 + threadIdx.x;       // 8192 threads
    for (int chunk = t0; chunk < 128 * 1056; chunk += 8192) {
        int o  = chunk / 1056;
        int cw = chunk - o * 1056;
        int c0 = cw * 8;
        f16x8 v;
        if (c0 + 8 <= SIGCH) {
            const float* src = w_out + (size_t)o * SIGCH + c0;
            float4 a = *(const float4*)src;
            float4 b = *(const float4*)(src + 4);
            v = (f16x8){(f16)a.x,(f16)a.y,(f16)a.z,(f16)a.w,
                        (f16)b.x,(f16)b.y,(f16)b.z,(f16)b.w};
        } else {
#pragma unroll
            for (int e = 0; e < 8; ++e) {
                int c = c0 + e;
                v[e] = (c < SIGCH) ? (f16)w_out[(size_t)o * SIGCH + c] : (f16)0.f;
            }
        }
        *(f16x8*)(wh + (size_t)o * SIGP + c0) = v;
    }
}

// ---------------------------------------------------------------------------
// Kernel 1: fused augment (MFMA conv) + signature-as-mini-GEMM (MFMA,
// operand-swapped so sig stores are f16x4 channel runs).
// 512 blocks: 4 batches, 1 wave/batch. LDS 49.5 KB -> 3 blocks/CU.
// ---------------------------------------------------------------------------
__global__ __launch_bounds__(256, 3) void k_augsig(
    const float* __restrict__ x,  const f16* __restrict__ wA, const float* __restrict__ b1,
    const float* __restrict__ w2, const float* __restrict__ b2,
    const float* __restrict__ w3, const float* __restrict__ b3,
    f16* __restrict__ sig)
{
    // LDS pool 12388 floats = 49.55 KB:
    //  [0..9408)      per-batch sig scratch, f16 units: batch w at f16 off w*4704
    //                 dtr 0..800 | atr 800..1600 | etr 1600..2400 | V 2400..4704
    //                 early aliases: xs @0 (4272 f32), xp16/h1s @4272 (2304 f32)
    //  [9408..12032)  pprev (4 x 656 f32)
    //  [12032..12388) wsmall
    __shared__ float pool[12388];
    float* xs    = pool;
    f16*   xp16  = (f16*)(pool + 4272);
    float* h1s   = (float*)xp16;
    float* pprev = pool + 9408;
    float* wsmall= pool + 12032;
    float* w2s = wsmall;        float* b2s = wsmall + 256;
    float* w3s = wsmall + 272;  float* b3s = wsmall + 336;
    float* b1s = wsmall + 340;

    const int tid  = threadIdx.x;
    const int b0   = blockIdx.x * 4;
    const int lane = tid & 63;
    const int w    = tid >> 6;
    const int n16  = lane & 15;
    const int q4   = lane >> 4;

    for (int i = tid; i < 4 * 1050; i += 256) {
        int bl = i / 1050; int t = i - bl * 1050;
        xs[bl * 1068 + t] = x[(size_t)b0 * 1050 + i];
    }
    if (tid < 256) w2s[tid] = w2[tid];
    if (tid < 16)  b2s[tid] = b2[tid];
    if (tid < 64)  w3s[tid] = w3[tid];
    if (tid < 4)   b3s[tid] = b3[tid];
    if (tid < 16)  b1s[tid] = b1[tid];

    // coalesced conv-weight fragments (b128 per lane, L2-resident after k_prep)
    f16x8 wa[20];
#pragma unroll
    for (int g = 0; g < 20; ++g) wa[g] = *(const f16x8*)(wA + g * 512 + lane * 8);
    __syncthreads();

    // ---- build xp16: [bl][pos][c], c padded to 16 (c=15 -> 0)
    for (int r = tid; r < 280; r += 256) {
        int bl = r / 70; int pos = r - bl * 70;
        const float* src = xs + bl * 1068 + pos * 15;
        f16* dst = xp16 + bl * 1152 + pos * 16;
#pragma unroll
        for (int c = 0; c < 15; ++c) dst[c] = (f16)src[c];
        dst[15] = (f16)0.f;
    }
    __syncthreads();

    // ---- conv via MFMA
    f32x4 cacc[2];
#pragma unroll
    for (int tile = 0; tile < 2; ++tile) {
        const int pos0 = tile * 15;
        f32x4 acc = {0.f, 0.f, 0.f, 0.f};
#pragma unroll
        for (int g = 0; g < 20; ++g) {
            const f16x8 bf = *(const f16x8*)&xp16[w * 1152 +
                (pos0 + n16 + 2 * g + (q4 >> 1)) * 16 + (q4 & 1) * 8];
            acc = __builtin_amdgcn_mfma_f32_16x16x32_f16(wa[g], bf, acc, 0, 0, 0);
        }
        cacc[tile] = acc;
    }
    __syncthreads();            // xp16 reads done before h1s alias write

#pragma unroll
    for (int tile = 0; tile < 2; ++tile) {
        int pos = tile * 15 + n16;
#pragma unroll
        for (int r = 0; r < 4; ++r) {
            int h = q4 * 4 + r;
            h1s[(w * 31 + pos) * 17 + h] = fmaxf(cacc[tile][r] + b1s[h], 0.f);
        }
    }
    __syncthreads();

    // ---- small MLPs; write path rows into pprev (LDS)
    if (tid < 124) {
        const int bl2 = tid / 31;
        const int pos = tid - bl2 * 31;
        float hr[16];
#pragma unroll
        for (int c2 = 0; c2 < 16; ++c2) hr[c2] = h1s[tid * 17 + c2];
        float h2[16];
#pragma unroll
        for (int o = 0; o < 16; ++o) {
            float s = b2s[o];
#pragma unroll
            for (int c2 = 0; c2 < 16; ++c2) s += w2s[o * 16 + c2] * hr[c2];
            h2[o] = fmaxf(s, 0.f);
        }
        float h3[4];
#pragma unroll
        for (int f = 0; f < 4; ++f) {
            float s = b3s[f];
#pragma unroll
            for (int c2 = 0; c2 < 16; ++c2) s += w3s[f * 16 + c2] * h2[c2];
            h3[f] = s;
        }
        float* pr = pprev + bl2 * 656 + 20 + pos * 20;
#pragma unroll
        for (int d = 0; d < D_INC; ++d) pr[d] = xs[bl2 * 1068 + (pos + 39) * 15 + d];
        pr[15] = (float)pos * (1.0f / 30.0f);
#pragma unroll
        for (int f = 0; f < 4; ++f) pr[16 + f] = h3[f];
    } else {
        int z = tid - 124;
        if (z < 80) pprev[(z / 20) * 656 + (z % 20)] = 0.f;
    }
    __syncthreads();           // pprev complete; xs/xp16 dead -> scratch alias OK

    // ---- per-batch f16 scratch
    float* pp   = pprev + w * 656;
    f16*   scr  = (f16*)pool + w * 4704;   // 9408 B/batch, 16B-aligned
    f16*   dtr  = scr;                     // [c][t] stride 40 f16 (80 B)
    f16*   atr  = scr + 800;
    f16*   etr  = scr + 1600;
    f16*   Vb   = scr + 2400;              // [n<32][k<64] stride 72 f16 (144 B)

    // (a) transposed d / A / E (f32 math, f16 store)
    for (int e = lane; e < 620; e += 64) {
        int c = e / 31, t = e - c * 31;
        float p0 = pp[t * 20 + c];
        float d  = pp[(t + 1) * 20 + c] - p0;
        dtr[c * 40 + t] = (f16)d;
        atr[c * 40 + t] = (f16)(p0 + 0.5f * d);
        etr[c * 40 + t] = (f16)(0.5f * p0 + d * (1.0f / 6.0f));
    }
    if (lane < 20) {
        dtr[lane * 40 + 31] = (f16)0.f;
        atr[lane * 40 + 31] = (f16)0.f;
        etr[lane * 40 + 31] = (f16)0.f;
    }
    __syncthreads();

    // (b) V: rows 0..19 = [SufD | d]; row 20 = ones|0 (s2); rows 21..31 = 0
    if (lane < 20) {
        f16* vr = Vb + lane * 72;
        float s = 0.f;
        for (int t = 30; t >= 0; --t) {
            float dv = (float)dtr[lane * 40 + t];
            vr[t]      = (f16)s;
            vr[32 + t] = (f16)dv;
            s += dv;
        }
        vr[31] = (f16)0.f;
        vr[63] = (f16)0.f;
    } else if (lane == 20) {
        f16* vr = Vb + 20 * 72;
        for (int k = 0; k < 64; ++k) vr[k] = (k < 31) ? (f16)1.f : (f16)0.f;
    }
    for (int e = lane; e < 11 * 32; e += 64) {       // zero rows 21..31
        int row = 21 + (e >> 5);
        int kk  = (e & 31) * 2;
        *(f16x2*)(Vb + row * 72 + kk) = (f16x2){(f16)0.f, (f16)0.f};
    }
    __syncthreads();

    // hoisted V fragments (A-operand role): rows nt*16+n16, k-window kc*32
    f16x8 bf[2][2];
#pragma unroll
    for (int kc = 0; kc < 2; ++kc)
#pragma unroll
        for (int nt = 0; nt < 2; ++nt)
            bf[kc][nt] = *(const f16x8*)(Vb + (nt * 16 + n16) * 72 + kc * 32 + q4 * 8);

    const int b = b0 + w;
    f16* sg = sig + (size_t)b * SIGP;

    // m-loop: 25 tiles of 16 pairs; UE frags in registers (pk_mul f16)
    for (int mt = 0; mt < 25; ++mt) {
        const int p = mt * 16 + n16;                 // p < 400 always
        const int i = p / 20, j = p - i * 20;
        f16x8 av = *(const f16x8*)(atr + i * 40 + q4 * 8);
        f16x8 ev = *(const f16x8*)(etr + i * 40 + q4 * 8);
        f16x8 dv = *(const f16x8*)(dtr + j * 40 + q4 * 8);
        f16x8 uf = av * dv;
        f16x8 ef = ev * dv;

        f32x4 a0 = {0.f,0.f,0.f,0.f}, a1 = {0.f,0.f,0.f,0.f};
        a0 = __builtin_amdgcn_mfma_f32_16x16x32_f16(bf[0][0], uf, a0, 0, 0, 0);
        a0 = __builtin_amdgcn_mfma_f32_16x16x32_f16(bf[1][0], ef, a0, 0, 0, 0);
        a1 = __builtin_amdgcn_mfma_f32_16x16x32_f16(bf[0][1], uf, a1, 0, 0, 0);
        a1 = __builtin_amdgcn_mfma_f32_16x16x32_f16(bf[1][1], ef, a1, 0, 0, 0);

        // D[c][p]: lane col = p-in-tile (n16), rows = c = (tile16) + q4*4 + r
        f16x4 s0 = {(f16)a0[0], (f16)a0[1], (f16)a0[2], (f16)a0[3]};
        *(f16x4*)(sg + 420 + p * 20 + q4 * 4) = s0;          // channels q4*4..+3
        if (q4 == 0) {
            f16x4 s1v = {(f16)a1[0], (f16)a1[1], (f16)a1[2], (f16)a1[3]};
            *(f16x4*)(sg + 420 + p * 20 + 16) = s1v;         // channels 16..19
        } else if (q4 == 1) {
            sg[20 + p] = (f16)a1[0];                         // s2 (ones row 20)
        }
    }

    if (lane < 20) sg[lane] = (f16)pp[620 + lane];          // s1 = path[30]
    if (lane < 28) sg[SIGCH + lane] = (f16)0.f;             // zero K pad
}

// ---------------------------------------------------------------------------
// Kernel 2: fp16 MFMA GEMM, BM32/BN128, split-K 11 — LDS-free, barrier-free.
// Row-major [M][K] with k-contiguous f16x8 IS the 16x16x32 fragment layout,
// so fragments load straight from global: A (sigh) streamed once from HBM
// (4 waves share 4 KB/iter via L1), B (wh, 2.1 MB) is L2-resident.
// No ds_write/ds_read round trip, no vmcnt(0)-drain-per-iter, no barriers:
// the compiler pipelines loads across iterations freely.
// Accumulation order identical to the previous LDS version (bit-identical z).
// ---------------------------------------------------------------------------
__global__ __launch_bounds__(256, 4) void k_gemm(const f16* __restrict__ sigh,
                                                 const f16* __restrict__ wh,
                                                 float* __restrict__ z_part)
{
    const int tid = threadIdx.x;
    const int l   = tid & 63;
    const int wv  = tid >> 6;        // n-tile (32 cols per wave)
    const int mt  = blockIdx.x / KSPLIT;
    const int s   = blockIdx.x - mt * KSPLIT;
    const int m0  = mt * 32;
    const int kb  = s * KLEN;
    const int kg   = l >> 4;         // k-quad 0..3 -> k-offset kg*8
    const int mrow = l & 15;

    const f16* a0p = sigh + (size_t)(m0 + mrow) * SIGP + kb + kg * 8;
    const f16* a1p = a0p + (size_t)16 * SIGP;
    const f16* b0p = wh   + (size_t)(wv * 32 + mrow) * SIGP + kb + kg * 8;
    const f16* b1p = b0p + (size_t)16 * SIGP;

    const f32x4 z4 = {0.f, 0.f, 0.f, 0.f};
    f32x4 acc[2][2];
    acc[0][0] = z4; acc[0][1] = z4; acc[1][0] = z4; acc[1][1] = z4;

#pragma unroll 2
    for (int ks = 0; ks < 24; ++ks) {            // 24 k-steps of 32 = KLEN
        const int ko = ks * 32;
        f16x8 aF0 = *(const f16x8*)(a0p + ko);
        f16x8 aF1 = *(const f16x8*)(a1p + ko);
        f16x8 bF0 = *(const f16x8*)(b0p + ko);
        f16x8 bF1 = *(const f16x8*)(b1p + ko);
        acc[0][0] = __builtin_amdgcn_mfma_f32_16x16x32_f16(aF0, bF0, acc[0][0], 0, 0, 0);
        acc[0][1] = __builtin_amdgcn_mfma_f32_16x16x32_f16(aF0, bF1, acc[0][1], 0, 0, 0);
        acc[1][0] = __builtin_amdgcn_mfma_f32_16x16x32_f16(aF1, bF0, acc[1][0], 0, 0, 0);
        acc[1][1] = __builtin_amdgcn_mfma_f32_16x16x32_f16(aF1, bF1, acc[1][1], 0, 0, 0);
    }

#pragma unroll
    for (int m2 = 0; m2 < 2; ++m2) {
#pragma unroll
        for (int n2 = 0; n2 < 2; ++n2) {
            int n = wv * 32 + n2 * 16 + (l & 15);
#pragma unroll
            for (int r = 0; r < 4; ++r) {
                int m = m0 + m2 * 16 + (l >> 4) * 4 + r;
                z_part[((size_t)s * B_TOT + m) * NOUT + n] = acc[m2][n2][r];
            }
        }
    }
}

// ---------------------------------------------------------------------------
// Kernel 3: reduce 11 split-K partials, add bias, softplus on second half.
// float4 per thread (o-groups never straddle the 64 boundary).
// ---------------------------------------------------------------------------
__global__ __launch_bounds__(256) void k_final(const float* __restrict__ z_part,
                                               const float* __restrict__ b_out,
                                               float* __restrict__ out)
{
    int idx = blockIdx.x * 256 + threadIdx.x;   // 65536 threads, 4 outputs each
    int b  = idx >> 5;
    int o4 = (idx & 31) << 2;                   // 0,4,...,124
    float4 z = *(const float4*)(b_out + o4);
#pragma unroll
    for (int s = 0; s < KSPLIT; ++s) {
        const float4 p = *(const float4*)(z_part + ((size_t)s * B_TOT + b) * NOUT + o4);
        z.x += p.x; z.y += p.y; z.z += p.z; z.w += p.w;
    }
    if (o4 < 64) {
        *(float4*)(out + (size_t)b * 64 + o4) = z;
    } else {
        float4 sp;
        sp.x = fmaxf(z.x, 0.f) + log1pf(expf(-fabsf(z.x)));
        sp.y = fmaxf(z.y, 0.f) + log1pf(expf(-fabsf(z.y)));
        sp.z = fmaxf(z.z, 0.f) + log1pf(expf(-fabsf(z.z)));
        sp.w = fmaxf(z.w, 0.f) + log1pf(expf(-fabsf(z.w)));
        *(float4*)(out + 131072 + (size_t)b * 64 + (o4 - 64)) = sp;
    }
}

// ---------------------------------------------------------------------------
extern "C" void kernel_launch(void* const* d_in, const int* in_sizes, int n_in,
                              void* d_out, int out_size, void* d_ws, size_t ws_size,
                              hipStream_t stream)
{
    const float* x     = (const float*)d_in[0];
    const float* w1    = (const float*)d_in[2];
    const float* b1    = (const float*)d_in[3];
    const float* w2    = (const float*)d_in[4];
    const float* b2    = (const float*)d_in[5];
    const float* w3    = (const float*)d_in[6];
    const float* b3    = (const float*)d_in[7];
    const float* w_out = (const float*)d_in[8];
    const float* b_out = (const float*)d_in[9];
    float* out = (float*)d_out;

    // float-unit offsets: N f16 elements occupy N/2 float units.
    float* ws    = (float*)d_ws;
    f16*   sigh  = (f16*)ws;                        // 2048*8448 f16 = 8,650,752 fu
    f16*   wh    = (f16*)(ws + 8650752);            // 128*8448 f16  =   540,672 fu
    f16*   wA    = (f16*)(ws + 9191424);            // 10,240 f16    =     5,120 fu
    float* zpart = ws + 9196544;                    // 11*2048*128   = 2,883,584 f
    // total 12,080,128 floats ~= 48.3 MB

    hipLaunchKernelGGL(k_prep,   dim3(33),   dim3(256), 0, stream, w1, w_out, wA, wh);
    hipLaunchKernelGGL(k_augsig, dim3(512),  dim3(256), 0, stream,
                       x, wA, b1, w2, b2, w3, b3, sigh);
    hipLaunchKernelGGL(k_gemm,   dim3(704),  dim3(256), 0, stream, sigh, wh, zpart);
    hipLaunchKernelGGL(k_final,  dim3(256),  dim3(256), 0, stream, zpart, b_out, out);
}

// Round 2
// 139.467 us; speedup vs baseline: 1.0385x; 1.0385x over previous
//
#include <hip/hip_runtime.h>
#include <math.h>

#define B_TOT 2048
#define D_INC 15
#define KW    40
#define CCH   20
#define LP    31
#define SIGCH 8420
#define SIGP  8448   // padded K; 8448 = 11*768, 768 = 12*64
#define NOUT  128
#define KSPLIT 11
#define KLEN  768    // per-split K: 24 k-steps of 32

typedef _Float16 f16;
typedef _Float16 f16x8 __attribute__((ext_vector_type(8)));
typedef _Float16 f16x4 __attribute__((ext_vector_type(4)));
typedef _Float16 f16x2 __attribute__((ext_vector_type(2)));
typedef float    f32x4 __attribute__((ext_vector_type(4)));

// ---------------------------------------------------------------------------
// Kernel 0: prep conv weights into MFMA A-fragment layout (fp16).
// 1 block only; w_out conversion stays in k_augsig's tail blocks so it
// OVERLAPS augsig compute (moving it here cost ~8 us serial in r1).
// ---------------------------------------------------------------------------
__global__ __launch_bounds__(256) void k_prep(const float* __restrict__ w1,
                                              f16* __restrict__ wA)
{
    const int ln = threadIdx.x & 63;
    const int wv = threadIdx.x >> 6;
    const int h  = ln & 15;
    const int q4 = ln >> 4;
    for (int gi = 0; gi < 5; ++gi) {
        int g = wv * 5 + gi;
        f16x8 v;
#pragma unroll
        for (int j = 0; j < 8; ++j) {
            int kq = q4 * 8 + j;
            int kk = 2 * g + (kq >> 4);
            int c  = kq & 15;
            v[j] = (c < D_INC) ? (f16)w1[h * 600 + c * 40 + kk] : (f16)0.f;
        }
        *(f16x8*)(wA + g * 512 + ln * 8) = v;
    }
}

// ---------------------------------------------------------------------------
// Kernel 1: fused augment (MFMA conv) + signature-as-mini-GEMM (MFMA,
// operand-swapped so sig stores are f16x4 channel runs).
// Blocks 0..511: 4 batches, 1 wave/batch. Blocks 512..543: w_out->f16
// convert (overlapped with compute blocks — do not move to k_prep).
// LDS 49.5 KB -> 3 blocks/CU.
// ---------------------------------------------------------------------------
__global__ __launch_bounds__(256, 3) void k_augsig(
    const float* __restrict__ x,  const f16* __restrict__ wA, const float* __restrict__ b1,
    const float* __restrict__ w2, const float* __restrict__ b2,
    const float* __restrict__ w3, const float* __restrict__ b3,
    const float* __restrict__ w_out, f16* __restrict__ wh, f16* __restrict__ sig)
{
    if (blockIdx.x >= 512) {
        int t0 = (blockIdx.x - 512) * 256 + threadIdx.x;     // 8192 threads
        for (int chunk = t0; chunk < 128 * 1056; chunk += 8192) {
            int o  = chunk / 1056;
            int cw = chunk - o * 1056;
            int c0 = cw * 8;
            f16x8 v;
            if (c0 + 8 <= SIGCH) {
                const float* src = w_out + (size_t)o * SIGCH + c0;
                float4 a = *(const float4*)src;
                float4 b = *(const float4*)(src + 4);
                v = (f16x8){(f16)a.x,(f16)a.y,(f16)a.z,(f16)a.w,
                            (f16)b.x,(f16)b.y,(f16)b.z,(f16)b.w};
            } else {
#pragma unroll
                for (int e = 0; e < 8; ++e) {
                    int c = c0 + e;
                    v[e] = (c < SIGCH) ? (f16)w_out[(size_t)o * SIGCH + c] : (f16)0.f;
                }
            }
            *(f16x8*)(wh + (size_t)o * SIGP + c0) = v;
        }
        return;
    }

    // LDS pool 12388 floats = 49.55 KB:
    //  [0..9408)      per-batch sig scratch, f16 units: batch w at f16 off w*4704
    //                 dtr 0..800 | atr 800..1600 | etr 1600..2400 | V 2400..4704
    //                 early aliases: xs @0 (4272 f32), xp16/h1s @4272 (2304 f32)
    //  [9408..12032)  pprev (4 x 656 f32)
    //  [12032..12388) wsmall
    __shared__ float pool[12388];
    float* xs    = pool;
    f16*   xp16  = (f16*)(pool + 4272);
    float* h1s   = (float*)xp16;
    float* pprev = pool + 9408;
    float* wsmall= pool + 12032;
    float* w2s = wsmall;        float* b2s = wsmall + 256;
    float* w3s = wsmall + 272;  float* b3s = wsmall + 336;
    float* b1s = wsmall + 340;

    const int tid  = threadIdx.x;
    const int b0   = blockIdx.x * 4;
    const int lane = tid & 63;
    const int w    = tid >> 6;
    const int n16  = lane & 15;
    const int q4   = lane >> 4;

    for (int i = tid; i < 4 * 1050; i += 256) {
        int bl = i / 1050; int t = i - bl * 1050;
        xs[bl * 1068 + t] = x[(size_t)b0 * 1050 + i];
    }
    if (tid < 256) w2s[tid] = w2[tid];
    if (tid < 16)  b2s[tid] = b2[tid];
    if (tid < 64)  w3s[tid] = w3[tid];
    if (tid < 4)   b3s[tid] = b3[tid];
    if (tid < 16)  b1s[tid] = b1[tid];

    // coalesced conv-weight fragments (b128 per lane, L2-resident after k_prep)
    f16x8 wa[20];
#pragma unroll
    for (int g = 0; g < 20; ++g) wa[g] = *(const f16x8*)(wA + g * 512 + lane * 8);
    __syncthreads();

    // ---- build xp16: [bl][pos][c], c padded to 16 (c=15 -> 0)
    for (int r = tid; r < 280; r += 256) {
        int bl = r / 70; int pos = r - bl * 70;
        const float* src = xs + bl * 1068 + pos * 15;
        f16* dst = xp16 + bl * 1152 + pos * 16;
#pragma unroll
        for (int c = 0; c < 15; ++c) dst[c] = (f16)src[c];
        dst[15] = (f16)0.f;
    }
    __syncthreads();

    // ---- conv via MFMA
    f32x4 cacc[2];
#pragma unroll
    for (int tile = 0; tile < 2; ++tile) {
        const int pos0 = tile * 15;
        f32x4 acc = {0.f, 0.f, 0.f, 0.f};
#pragma unroll
        for (int g = 0; g < 20; ++g) {
            const f16x8 bf = *(const f16x8*)&xp16[w * 1152 +
                (pos0 + n16 + 2 * g + (q4 >> 1)) * 16 + (q4 & 1) * 8];
            acc = __builtin_amdgcn_mfma_f32_16x16x32_f16(wa[g], bf, acc, 0, 0, 0);
        }
        cacc[tile] = acc;
    }
    __syncthreads();            // xp16 reads done before h1s alias write

#pragma unroll
    for (int tile = 0; tile < 2; ++tile) {
        int pos = tile * 15 + n16;
#pragma unroll
        for (int r = 0; r < 4; ++r) {
            int h = q4 * 4 + r;
            h1s[(w * 31 + pos) * 17 + h] = fmaxf(cacc[tile][r] + b1s[h], 0.f);
        }
    }
    __syncthreads();

    // ---- small MLPs; write path rows into pprev (LDS)
    if (tid < 124) {
        const int bl2 = tid / 31;
        const int pos = tid - bl2 * 31;
        float hr[16];
#pragma unroll
        for (int c2 = 0; c2 < 16; ++c2) hr[c2] = h1s[tid * 17 + c2];
        float h2[16];
#pragma unroll
        for (int o = 0; o < 16; ++o) {
            float s = b2s[o];
#pragma unroll
            for (int c2 = 0; c2 < 16; ++c2) s += w2s[o * 16 + c2] * hr[c2];
            h2[o] = fmaxf(s, 0.f);
        }
        float h3[4];
#pragma unroll
        for (int f = 0; f < 4; ++f) {
            float s = b3s[f];
#pragma unroll
            for (int c2 = 0; c2 < 16; ++c2) s += w3s[f * 16 + c2] * h2[c2];
            h3[f] = s;
        }
        float* pr = pprev + bl2 * 656 + 20 + pos * 20;
#pragma unroll
        for (int d = 0; d < D_INC; ++d) pr[d] = xs[bl2 * 1068 + (pos + 39) * 15 + d];
        pr[15] = (float)pos * (1.0f / 30.0f);
#pragma unroll
        for (int f = 0; f < 4; ++f) pr[16 + f] = h3[f];
    } else {
        int z = tid - 124;
        if (z < 80) pprev[(z / 20) * 656 + (z % 20)] = 0.f;
    }
    __syncthreads();           // pprev complete; xs/xp16 dead -> scratch alias OK

    // ---- per-batch f16 scratch
    float* pp   = pprev + w * 656;
    f16*   scr  = (f16*)pool + w * 4704;   // 9408 B/batch, 16B-aligned
    f16*   dtr  = scr;                     // [c][t] stride 40 f16 (80 B)
    f16*   atr  = scr + 800;
    f16*   etr  = scr + 1600;
    f16*   Vb   = scr + 2400;              // [n<32][k<64] stride 72 f16 (144 B)

    // (a) transposed d / A / E (f32 math, f16 store)
    for (int e = lane; e < 620; e += 64) {
        int c = e / 31, t = e - c * 31;
        float p0 = pp[t * 20 + c];
        float d  = pp[(t + 1) * 20 + c] - p0;
        dtr[c * 40 + t] = (f16)d;
        atr[c * 40 + t] = (f16)(p0 + 0.5f * d);
        etr[c * 40 + t] = (f16)(0.5f * p0 + d * (1.0f / 6.0f));
    }
    if (lane < 20) {
        dtr[lane * 40 + 31] = (f16)0.f;
        atr[lane * 40 + 31] = (f16)0.f;
        etr[lane * 40 + 31] = (f16)0.f;
    }
    __syncthreads();

    // (b) V: rows 0..19 = [SufD | d]; row 20 = ones|0 (s2); rows 21..31 = 0
    if (lane < 20) {
        f16* vr = Vb + lane * 72;
        float s = 0.f;
        for (int t = 30; t >= 0; --t) {
            float dv = (float)dtr[lane * 40 + t];
            vr[t]      = (f16)s;
            vr[32 + t] = (f16)dv;
            s += dv;
        }
        vr[31] = (f16)0.f;
        vr[63] = (f16)0.f;
    } else if (lane == 20) {
        f16* vr = Vb + 20 * 72;
        for (int k = 0; k < 64; ++k) vr[k] = (k < 31) ? (f16)1.f : (f16)0.f;
    }
    for (int e = lane; e < 11 * 32; e += 64) {       // zero rows 21..31
        int row = 21 + (e >> 5);
        int kk  = (e & 31) * 2;
        *(f16x2*)(Vb + row * 72 + kk) = (f16x2){(f16)0.f, (f16)0.f};
    }
    __syncthreads();

    // hoisted V fragments (A-operand role): rows nt*16+n16, k-window kc*32
    f16x8 bf[2][2];
#pragma unroll
    for (int kc = 0; kc < 2; ++kc)
#pragma unroll
        for (int nt = 0; nt < 2; ++nt)
            bf[kc][nt] = *(const f16x8*)(Vb + (nt * 16 + n16) * 72 + kc * 32 + q4 * 8);

    const int b = b0 + w;
    f16* sg = sig + (size_t)b * SIGP;

    // m-loop: 25 tiles of 16 pairs; UE frags in registers (pk_mul f16)
    for (int mt = 0; mt < 25; ++mt) {
        const int p = mt * 16 + n16;                 // p < 400 always
        const int i = p / 20, j = p - i * 20;
        f16x8 av = *(const f16x8*)(atr + i * 40 + q4 * 8);
        f16x8 ev = *(const f16x8*)(etr + i * 40 + q4 * 8);
        f16x8 dv = *(const f16x8*)(dtr + j * 40 + q4 * 8);
        f16x8 uf = av * dv;
        f16x8 ef = ev * dv;

        f32x4 a0 = {0.f,0.f,0.f,0.f}, a1 = {0.f,0.f,0.f,0.f};
        a0 = __builtin_amdgcn_mfma_f32_16x16x32_f16(bf[0][0], uf, a0, 0, 0, 0);
        a0 = __builtin_amdgcn_mfma_f32_16x16x32_f16(bf[1][0], ef, a0, 0, 0, 0);
        a1 = __builtin_amdgcn_mfma_f32_16x16x32_f16(bf[0][1], uf, a1, 0, 0, 0);
        a1 = __builtin_amdgcn_mfma_f32_16x16x32_f16(bf[1][1], ef, a1, 0, 0, 0);

        // D[c][p]: lane col = p-in-tile (n16), rows = c = (tile16) + q4*4 + r
        f16x4 s0 = {(f16)a0[0], (f16)a0[1], (f16)a0[2], (f16)a0[3]};
        *(f16x4*)(sg + 420 + p * 20 + q4 * 4) = s0;          // channels q4*4..+3
        if (q4 == 0) {
            f16x4 s1v = {(f16)a1[0], (f16)a1[1], (f16)a1[2], (f16)a1[3]};
            *(f16x4*)(sg + 420 + p * 20 + 16) = s1v;         // channels 16..19
        } else if (q4 == 1) {
            sg[20 + p] = (f16)a1[0];                         // s2 (ones row 20)
        }
    }

    if (lane < 20) sg[lane] = (f16)pp[620 + lane];          // s1 = path[30]
    if (lane < 28) sg[SIGCH + lane] = (f16)0.f;             // zero K pad
}

// ---------------------------------------------------------------------------
// Kernel 2: fp16 MFMA GEMM, BM32/BN128, split-K 11 — LDS-free, barrier-free,
// with an explicit 2-stage named-register pipeline (loads issued 2 k-steps =
// 8 loads ahead of their MFMAs, so the compiler emits counted vmcnt waits
// instead of a shallow window). Row-major k-contiguous f16x8 IS the
// 16x16x32 fragment layout, so fragments load straight from global:
// A (sigh) streamed once from HBM, B (wh, 2.1 MB) L2-resident.
// Accumulation order identical to the LDS version (bit-identical z).
// ---------------------------------------------------------------------------
__global__ __launch_bounds__(256) void k_gemm(const f16* __restrict__ sigh,
                                              const f16* __restrict__ wh,
                                              float* __restrict__ z_part)
{
    const int tid = threadIdx.x;
    const int l   = tid & 63;
    const int wv  = tid >> 6;        // n-tile (32 cols per wave)
    const int mt  = blockIdx.x / KSPLIT;
    const int s   = blockIdx.x - mt * KSPLIT;
    const int m0  = mt * 32;
    const int kb  = s * KLEN;
    const int kg   = l >> 4;         // k-quad 0..3 -> k-offset kg*8
    const int mrow = l & 15;

    const f16* a0p = sigh + (size_t)(m0 + mrow) * SIGP + kb + kg * 8;
    const f16* a1p = a0p + (size_t)16 * SIGP;
    const f16* b0p = wh   + (size_t)(wv * 32 + mrow) * SIGP + kb + kg * 8;
    const f16* b1p = b0p + (size_t)16 * SIGP;

    const f32x4 z4 = {0.f, 0.f, 0.f, 0.f};
    f32x4 acc00 = z4, acc01 = z4, acc10 = z4, acc11 = z4;

    // 2-stage pipeline, named registers (no runtime-indexed arrays).
    f16x8 xa0 = *(const f16x8*)(a0p);       // stage X: even k-step
    f16x8 xa1 = *(const f16x8*)(a1p);
    f16x8 xb0 = *(const f16x8*)(b0p);
    f16x8 xb1 = *(const f16x8*)(b1p);
    f16x8 ya0 = *(const f16x8*)(a0p + 32);  // stage Y: odd k-step
    f16x8 ya1 = *(const f16x8*)(a1p + 32);
    f16x8 yb0 = *(const f16x8*)(b0p + 32);
    f16x8 yb1 = *(const f16x8*)(b1p + 32);

#pragma unroll
    for (int it = 0; it < 12; ++it) {
        // ---- even k-step (2*it): consume X, prefetch 2*it+2 into X
        f16x8 ua0 = xa0, ua1 = xa1, ub0 = xb0, ub1 = xb1;
        if (it < 11) {
            const int ko = (2 * it + 2) * 32;
            xa0 = *(const f16x8*)(a0p + ko);
            xa1 = *(const f16x8*)(a1p + ko);
            xb0 = *(const f16x8*)(b0p + ko);
            xb1 = *(const f16x8*)(b1p + ko);
        }
        acc00 = __builtin_amdgcn_mfma_f32_16x16x32_f16(ua0, ub0, acc00, 0, 0, 0);
        acc01 = __builtin_amdgcn_mfma_f32_16x16x32_f16(ua0, ub1, acc01, 0, 0, 0);
        acc10 = __builtin_amdgcn_mfma_f32_16x16x32_f16(ua1, ub0, acc10, 0, 0, 0);
        acc11 = __builtin_amdgcn_mfma_f32_16x16x32_f16(ua1, ub1, acc11, 0, 0, 0);

        // ---- odd k-step (2*it+1): consume Y, prefetch 2*it+3 into Y
        f16x8 va0 = ya0, va1 = ya1, vb0 = yb0, vb1 = yb1;
        if (it < 11) {
            const int ko = (2 * it + 3) * 32;
            ya0 = *(const f16x8*)(a0p + ko);
            ya1 = *(const f16x8*)(a1p + ko);
            yb0 = *(const f16x8*)(b0p + ko);
            yb1 = *(const f16x8*)(b1p + ko);
        }
        acc00 = __builtin_amdgcn_mfma_f32_16x16x32_f16(va0, vb0, acc00, 0, 0, 0);
        acc01 = __builtin_amdgcn_mfma_f32_16x16x32_f16(va0, vb1, acc01, 0, 0, 0);
        acc10 = __builtin_amdgcn_mfma_f32_16x16x32_f16(va1, vb0, acc10, 0, 0, 0);
        acc11 = __builtin_amdgcn_mfma_f32_16x16x32_f16(va1, vb1, acc11, 0, 0, 0);
    }

#pragma unroll
    for (int m2 = 0; m2 < 2; ++m2) {
#pragma unroll
        for (int n2 = 0; n2 < 2; ++n2) {
            const f32x4 a = (m2 == 0) ? (n2 == 0 ? acc00 : acc01)
                                      : (n2 == 0 ? acc10 : acc11);
            int n = wv * 32 + n2 * 16 + (l & 15);
#pragma unroll
            for (int r = 0; r < 4; ++r) {
                int m = m0 + m2 * 16 + (l >> 4) * 4 + r;
                z_part[((size_t)s * B_TOT + m) * NOUT + n] = a[r];
            }
        }
    }
}

// ---------------------------------------------------------------------------
// Kernel 3: reduce 11 split-K partials, add bias, softplus on second half.
// float4 per thread (o-groups never straddle the 64 boundary).
// ---------------------------------------------------------------------------
__global__ __launch_bounds__(256) void k_final(const float* __restrict__ z_part,
                                               const float* __restrict__ b_out,
                                               float* __restrict__ out)
{
    int idx = blockIdx.x * 256 + threadIdx.x;   // 65536 threads, 4 outputs each
    int b  = idx >> 5;
    int o4 = (idx & 31) << 2;                   // 0,4,...,124
    float4 z = *(const float4*)(b_out + o4);
#pragma unroll
    for (int s = 0; s < KSPLIT; ++s) {
        const float4 p = *(const float4*)(z_part + ((size_t)s * B_TOT + b) * NOUT + o4);
        z.x += p.x; z.y += p.y; z.z += p.z; z.w += p.w;
    }
    if (o4 < 64) {
        *(float4*)(out + (size_t)b * 64 + o4) = z;
    } else {
        float4 sp;
        sp.x = fmaxf(z.x, 0.f) + log1pf(expf(-fabsf(z.x)));
        sp.y = fmaxf(z.y, 0.f) + log1pf(expf(-fabsf(z.y)));
        sp.z = fmaxf(z.z, 0.f) + log1pf(expf(-fabsf(z.z)));
        sp.w = fmaxf(z.w, 0.f) + log1pf(expf(-fabsf(z.w)));
        *(float4*)(out + 131072 + (size_t)b * 64 + (o4 - 64)) = sp;
    }
}

// ---------------------------------------------------------------------------
extern "C" void kernel_launch(void* const* d_in, const int* in_sizes, int n_in,
                              void* d_out, int out_size, void* d_ws, size_t ws_size,
                              hipStream_t stream)
{
    const float* x     = (const float*)d_in[0];
    const float* w1    = (const float*)d_in[2];
    const float* b1    = (const float*)d_in[3];
    const float* w2    = (const float*)d_in[4];
    const float* b2    = (const float*)d_in[5];
    const float* w3    = (const float*)d_in[6];
    const float* b3    = (const float*)d_in[7];
    const float* w_out = (const float*)d_in[8];
    const float* b_out = (const float*)d_in[9];
    float* out = (float*)d_out;

    // float-unit offsets: N f16 elements occupy N/2 float units.
    float* ws    = (float*)d_ws;
    f16*   sigh  = (f16*)ws;                        // 2048*8448 f16 = 8,650,752 fu
    f16*   wh    = (f16*)(ws + 8650752);            // 128*8448 f16  =   540,672 fu
    f16*   wA    = (f16*)(ws + 9191424);            // 10,240 f16    =     5,120 fu
    float* zpart = ws + 9196544;                    // 11*2048*128   = 2,883,584 f
    // total 12,080,128 floats ~= 48.3 MB

    hipLaunchKernelGGL(k_prep,   dim3(1),    dim3(256), 0, stream, w1, wA);
    hipLaunchKernelGGL(k_augsig, dim3(544),  dim3(256), 0, stream,
                       x, wA, b1, w2, b2, w3, b3, w_out, wh, sigh);
    hipLaunchKernelGGL(k_gemm,   dim3(704),  dim3(256), 0, stream, sigh, wh, zpart);
    hipLaunchKernelGGL(k_final,  dim3(256),  dim3(256), 0, stream, zpart, b_out, out);
}

// Round 4
// 133.810 us; speedup vs baseline: 1.0824x; 1.0423x over previous
//
#include <hip/hip_runtime.h>
#include <math.h>

#define B_TOT 2048
#define D_INC 15
#define KW    40
#define CCH   20
#define LP    31
#define SIGCH 8420
#define SIGP  8448   // padded K; 8448 = 11*768, 768 = 12*64
#define NOUT  128
#define KSPLIT 11
#define KLEN  768    // per-split K: 12 chunks of BK=64

typedef _Float16 f16;
typedef _Float16 f16x8 __attribute__((ext_vector_type(8)));
typedef _Float16 f16x4 __attribute__((ext_vector_type(4)));
typedef _Float16 f16x2 __attribute__((ext_vector_type(2)));
typedef float    f32x4 __attribute__((ext_vector_type(4)));

// async global->LDS DMA, 16 B per lane (dest = wave-uniform base + lane*16)
__device__ __forceinline__ void glds16(const f16* g, f16* l)
{
    __builtin_amdgcn_global_load_lds(
        (const __attribute__((address_space(1))) void*)g,
        (__attribute__((address_space(3))) void*)l, 16, 0, 0);
}

// DMA drain: global_load_lds counts in vmcnt; __syncthreads' fence is not
// guaranteed to include vmcnt(0) (r3 raced intermittently under graph
// replay). Force it before every barrier that publishes DMA'd LDS.
__device__ __forceinline__ void dma_drain()
{
    asm volatile("s_waitcnt vmcnt(0)" ::: "memory");
}

// ---------------------------------------------------------------------------
// Kernel 0: prep conv weights into MFMA A-fragment layout (fp16).
// 1 block only; w_out conversion stays in k_augsig's tail blocks so it
// OVERLAPS augsig compute (moving it here cost ~5 us serial in r1).
// ---------------------------------------------------------------------------
__global__ __launch_bounds__(256) void k_prep(const float* __restrict__ w1,
                                              f16* __restrict__ wA)
{
    const int ln = threadIdx.x & 63;
    const int wv = threadIdx.x >> 6;
    const int h  = ln & 15;
    const int q4 = ln >> 4;
    for (int gi = 0; gi < 5; ++gi) {
        int g = wv * 5 + gi;
        f16x8 v;
#pragma unroll
        for (int j = 0; j < 8; ++j) {
            int kq = q4 * 8 + j;
            int kk = 2 * g + (kq >> 4);
            int c  = kq & 15;
            v[j] = (c < D_INC) ? (f16)w1[h * 600 + c * 40 + kk] : (f16)0.f;
        }
        *(f16x8*)(wA + g * 512 + ln * 8) = v;
    }
}

// ---------------------------------------------------------------------------
// Kernel 1: fused augment (MFMA conv) + signature-as-mini-GEMM (MFMA,
// operand-swapped so sig stores are f16x4 channel runs).
// Blocks 0..511: 4 batches, 1 wave/batch. Blocks 512..543: w_out->f16
// convert (overlapped with compute blocks — do not move to k_prep).
// LDS 49.5 KB -> 3 blocks/CU.
// ---------------------------------------------------------------------------
__global__ __launch_bounds__(256, 3) void k_augsig(
    const float* __restrict__ x,  const f16* __restrict__ wA, const float* __restrict__ b1,
    const float* __restrict__ w2, const float* __restrict__ b2,
    const float* __restrict__ w3, const float* __restrict__ b3,
    const float* __restrict__ w_out, f16* __restrict__ wh, f16* __restrict__ sig)
{
    if (blockIdx.x >= 512) {
        int t0 = (blockIdx.x - 512) * 256 + threadIdx.x;     // 8192 threads
        for (int chunk = t0; chunk < 128 * 1056; chunk += 8192) {
            int o  = chunk / 1056;
            int cw = chunk - o * 1056;
            int c0 = cw * 8;
            f16x8 v;
            if (c0 + 8 <= SIGCH) {
                const float* src = w_out + (size_t)o * SIGCH + c0;
                float4 a = *(const float4*)src;
                float4 b = *(const float4*)(src + 4);
                v = (f16x8){(f16)a.x,(f16)a.y,(f16)a.z,(f16)a.w,
                            (f16)b.x,(f16)b.y,(f16)b.z,(f16)b.w};
            } else {
#pragma unroll
                for (int e = 0; e < 8; ++e) {
                    int c = c0 + e;
                    v[e] = (c < SIGCH) ? (f16)w_out[(size_t)o * SIGCH + c] : (f16)0.f;
                }
            }
            *(f16x8*)(wh + (size_t)o * SIGP + c0) = v;
        }
        return;
    }

    // LDS pool 12388 floats = 49.55 KB:
    //  [0..9408)      per-batch sig scratch, f16 units: batch w at f16 off w*4704
    //                 dtr 0..800 | atr 800..1600 | etr 1600..2400 | V 2400..4704
    //                 early aliases: xs @0 (4272 f32), xp16/h1s @4272 (2304 f32)
    //  [9408..12032)  pprev (4 x 656 f32)
    //  [12032..12388) wsmall
    __shared__ float pool[12388];
    float* xs    = pool;
    f16*   xp16  = (f16*)(pool + 4272);
    float* h1s   = (float*)xp16;
    float* pprev = pool + 9408;
    float* wsmall= pool + 12032;
    float* w2s = wsmall;        float* b2s = wsmall + 256;
    float* w3s = wsmall + 272;  float* b3s = wsmall + 336;
    float* b1s = wsmall + 340;

    const int tid  = threadIdx.x;
    const int b0   = blockIdx.x * 4;
    const int lane = tid & 63;
    const int w    = tid >> 6;
    const int n16  = lane & 15;
    const int q4   = lane >> 4;

    for (int i = tid; i < 4 * 1050; i += 256) {
        int bl = i / 1050; int t = i - bl * 1050;
        xs[bl * 1068 + t] = x[(size_t)b0 * 1050 + i];
    }
    if (tid < 256) w2s[tid] = w2[tid];
    if (tid < 16)  b2s[tid] = b2[tid];
    if (tid < 64)  w3s[tid] = w3[tid];
    if (tid < 4)   b3s[tid] = b3[tid];
    if (tid < 16)  b1s[tid] = b1[tid];

    // coalesced conv-weight fragments (b128 per lane, L2-resident after k_prep)
    f16x8 wa[20];
#pragma unroll
    for (int g = 0; g < 20; ++g) wa[g] = *(const f16x8*)(wA + g * 512 + lane * 8);
    __syncthreads();

    // ---- build xp16: [bl][pos][c], c padded to 16 (c=15 -> 0)
    for (int r = tid; r < 280; r += 256) {
        int bl = r / 70; int pos = r - bl * 70;
        const float* src = xs + bl * 1068 + pos * 15;
        f16* dst = xp16 + bl * 1152 + pos * 16;
#pragma unroll
        for (int c = 0; c < 15; ++c) dst[c] = (f16)src[c];
        dst[15] = (f16)0.f;
    }
    __syncthreads();

    // ---- conv via MFMA
    f32x4 cacc[2];
#pragma unroll
    for (int tile = 0; tile < 2; ++tile) {
        const int pos0 = tile * 15;
        f32x4 acc = {0.f, 0.f, 0.f, 0.f};
#pragma unroll
        for (int g = 0; g < 20; ++g) {
            const f16x8 bf = *(const f16x8*)&xp16[w * 1152 +
                (pos0 + n16 + 2 * g + (q4 >> 1)) * 16 + (q4 & 1) * 8];
            acc = __builtin_amdgcn_mfma_f32_16x16x32_f16(wa[g], bf, acc, 0, 0, 0);
        }
        cacc[tile] = acc;
    }
    __syncthreads();            // xp16 reads done before h1s alias write

#pragma unroll
    for (int tile = 0; tile < 2; ++tile) {
        int pos = tile * 15 + n16;
#pragma unroll
        for (int r = 0; r < 4; ++r) {
            int h = q4 * 4 + r;
            h1s[(w * 31 + pos) * 17 + h] = fmaxf(cacc[tile][r] + b1s[h], 0.f);
        }
    }
    __syncthreads();

    // ---- small MLPs; write path rows into pprev (LDS)
    if (tid < 124) {
        const int bl2 = tid / 31;
        const int pos = tid - bl2 * 31;
        float hr[16];
#pragma unroll
        for (int c2 = 0; c2 < 16; ++c2) hr[c2] = h1s[tid * 17 + c2];
        float h2[16];
#pragma unroll
        for (int o = 0; o < 16; ++o) {
            float s = b2s[o];
#pragma unroll
            for (int c2 = 0; c2 < 16; ++c2) s += w2s[o * 16 + c2] * hr[c2];
            h2[o] = fmaxf(s, 0.f);
        }
        float h3[4];
#pragma unroll
        for (int f = 0; f < 4; ++f) {
            float s = b3s[f];
#pragma unroll
            for (int c2 = 0; c2 < 16; ++c2) s += w3s[f * 16 + c2] * h2[c2];
            h3[f] = s;
        }
        float* pr = pprev + bl2 * 656 + 20 + pos * 20;
#pragma unroll
        for (int d = 0; d < D_INC; ++d) pr[d] = xs[bl2 * 1068 + (pos + 39) * 15 + d];
        pr[15] = (float)pos * (1.0f / 30.0f);
#pragma unroll
        for (int f = 0; f < 4; ++f) pr[16 + f] = h3[f];
    } else {
        int z = tid - 124;
        if (z < 80) pprev[(z / 20) * 656 + (z % 20)] = 0.f;
    }
    __syncthreads();           // pprev complete; xs/xp16 dead -> scratch alias OK

    // ---- per-batch f16 scratch
    float* pp   = pprev + w * 656;
    f16*   scr  = (f16*)pool + w * 4704;   // 9408 B/batch, 16B-aligned
    f16*   dtr  = scr;                     // [c][t] stride 40 f16 (80 B)
    f16*   atr  = scr + 800;
    f16*   etr  = scr + 1600;
    f16*   Vb   = scr + 2400;              // [n<32][k<64] stride 72 f16 (144 B)

    // (a) transposed d / A / E (f32 math, f16 store)
    for (int e = lane; e < 620; e += 64) {
        int c = e / 31, t = e - c * 31;
        float p0 = pp[t * 20 + c];
        float d  = pp[(t + 1) * 20 + c] - p0;
        dtr[c * 40 + t] = (f16)d;
        atr[c * 40 + t] = (f16)(p0 + 0.5f * d);
        etr[c * 40 + t] = (f16)(0.5f * p0 + d * (1.0f / 6.0f));
    }
    if (lane < 20) {
        dtr[lane * 40 + 31] = (f16)0.f;
        atr[lane * 40 + 31] = (f16)0.f;
        etr[lane * 40 + 31] = (f16)0.f;
    }
    __syncthreads();

    // (b) V: rows 0..19 = [SufD | d]; row 20 = ones|0 (s2); rows 21..31 = 0
    if (lane < 20) {
        f16* vr = Vb + lane * 72;
        float s = 0.f;
        for (int t = 30; t >= 0; --t) {
            float dv = (float)dtr[lane * 40 + t];
            vr[t]      = (f16)s;
            vr[32 + t] = (f16)dv;
            s += dv;
        }
        vr[31] = (f16)0.f;
        vr[63] = (f16)0.f;
    } else if (lane == 20) {
        f16* vr = Vb + 20 * 72;
        for (int k = 0; k < 64; ++k) vr[k] = (k < 31) ? (f16)1.f : (f16)0.f;
    }
    for (int e = lane; e < 11 * 32; e += 64) {       // zero rows 21..31
        int row = 21 + (e >> 5);
        int kk  = (e & 31) * 2;
        *(f16x2*)(Vb + row * 72 + kk) = (f16x2){(f16)0.f, (f16)0.f};
    }
    __syncthreads();

    // hoisted V fragments (A-operand role): rows nt*16+n16, k-window kc*32
    f16x8 bf[2][2];
#pragma unroll
    for (int kc = 0; kc < 2; ++kc)
#pragma unroll
        for (int nt = 0; nt < 2; ++nt)
            bf[kc][nt] = *(const f16x8*)(Vb + (nt * 16 + n16) * 72 + kc * 32 + q4 * 8);

    const int b = b0 + w;
    f16* sg = sig + (size_t)b * SIGP;

    // m-loop: 25 tiles of 16 pairs; UE frags in registers (pk_mul f16)
    for (int mt = 0; mt < 25; ++mt) {
        const int p = mt * 16 + n16;                 // p < 400 always
        const int i = p / 20, j = p - i * 20;
        f16x8 av = *(const f16x8*)(atr + i * 40 + q4 * 8);
        f16x8 ev = *(const f16x8*)(etr + i * 40 + q4 * 8);
        f16x8 dv = *(const f16x8*)(dtr + j * 40 + q4 * 8);
        f16x8 uf = av * dv;
        f16x8 ef = ev * dv;

        f32x4 a0 = {0.f,0.f,0.f,0.f}, a1 = {0.f,0.f,0.f,0.f};
        a0 = __builtin_amdgcn_mfma_f32_16x16x32_f16(bf[0][0], uf, a0, 0, 0, 0);
        a0 = __builtin_amdgcn_mfma_f32_16x16x32_f16(bf[1][0], ef, a0, 0, 0, 0);
        a1 = __builtin_amdgcn_mfma_f32_16x16x32_f16(bf[0][1], uf, a1, 0, 0, 0);
        a1 = __builtin_amdgcn_mfma_f32_16x16x32_f16(bf[1][1], ef, a1, 0, 0, 0);

        // D[c][p]: lane col = p-in-tile (n16), rows = c = (tile16) + q4*4 + r
        f16x4 s0 = {(f16)a0[0], (f16)a0[1], (f16)a0[2], (f16)a0[3]};
        *(f16x4*)(sg + 420 + p * 20 + q4 * 4) = s0;          // channels q4*4..+3
        if (q4 == 0) {
            f16x4 s1v = {(f16)a1[0], (f16)a1[1], (f16)a1[2], (f16)a1[3]};
            *(f16x4*)(sg + 420 + p * 20 + 16) = s1v;         // channels 16..19
        } else if (q4 == 1) {
            sg[20 + p] = (f16)a1[0];                         // s2 (ones row 20)
        }
    }

    if (lane < 20) sg[lane] = (f16)pp[620 + lane];          // s1 = path[30]
    if (lane < 28) sg[SIGCH + lane] = (f16)0.f;             // zero K pad
}

// ---------------------------------------------------------------------------
// Kernel 2: fp16 MFMA GEMM, BM32/BN128/BK64, split-K 11 — LDS-staged via
// global_load_lds width=16 DMA, double-buffered, ONE barrier per chunk.
// r3 lesson: the DMA counts in vmcnt and __syncthreads' fence did NOT
// reliably drain it -> explicit s_waitcnt vmcnt(0) before every barrier
// that publishes DMA'd data. Fragment order identical to r0 (bit-identical z).
// ---------------------------------------------------------------------------
__global__ __launch_bounds__(256) void k_gemm(const f16* __restrict__ sigh,
                                              const f16* __restrict__ wh,
                                              float* __restrict__ z_part)
{
    __shared__ f16 As[2][2048];
    __shared__ f16 Bs[2][8192];
    const int tid = threadIdx.x;
    const int l   = tid & 63;
    const int wv  = tid >> 6;
    const int mt  = blockIdx.x / KSPLIT;
    const int s   = blockIdx.x - mt * KSPLIT;
    const int m0  = mt * 32;
    const int kb  = s * KLEN;

    const f32x4 z4 = {0.f, 0.f, 0.f, 0.f};
    f32x4 acc[2][2];
    acc[0][0] = z4; acc[0][1] = z4; acc[1][0] = z4; acc[1][1] = z4;

    // per-lane global sources (16 B each); LDS dests are wave-uniform bases
    const f16* gA = sigh + (size_t)(m0 + (tid & 31)) * SIGP + kb + (tid >> 5) * 8;
    const f16* gB[4];
#pragma unroll
    for (int r = 0; r < 4; ++r) {
        int slot = r * 256 + tid;
        gB[r] = wh + (size_t)(slot & 127) * SIGP + kb + (slot >> 7) * 8;
    }

    const int kg   = l >> 4;
    const int mrow = l & 15;

    // prologue: stage chunk 0 into buffer 0
    glds16(gA, &As[0][wv * 512]);
#pragma unroll
    for (int r = 0; r < 4; ++r) glds16(gB[r], &Bs[0][r * 2048 + wv * 512]);
    dma_drain();
    __syncthreads();

    for (int ch = 0; ch < 12; ++ch) {
        const int cur = ch & 1;
        if (ch < 11) {                       // DMA next chunk into other buffer
            const int ko = (ch + 1) * 64;
            glds16(gA + ko, &As[cur ^ 1][wv * 512]);
#pragma unroll
            for (int r = 0; r < 4; ++r)
                glds16(gB[r] + ko, &Bs[cur ^ 1][r * 2048 + wv * 512]);
        }

#pragma unroll
        for (int kc = 0; kc < 2; ++kc) {
            f16x8 aF[2], bF[2];
#pragma unroll
            for (int m2 = 0; m2 < 2; ++m2)
                aF[m2] = *(const f16x8*)&As[cur][((kc * 4 + kg) * 32 + m2 * 16 + mrow) * 8];
#pragma unroll
            for (int n2 = 0; n2 < 2; ++n2)
                bF[n2] = *(const f16x8*)&Bs[cur][((kc * 4 + kg) * 128 + wv * 32 + n2 * 16 + mrow) * 8];
#pragma unroll
            for (int m2 = 0; m2 < 2; ++m2)
#pragma unroll
                for (int n2 = 0; n2 < 2; ++n2)
                    acc[m2][n2] = __builtin_amdgcn_mfma_f32_16x16x32_f16(aF[m2], bF[n2], acc[m2][n2], 0, 0, 0);
        }
        dma_drain();                         // next buffer's DMA fully landed
        __syncthreads();
    }

#pragma unroll
    for (int m2 = 0; m2 < 2; ++m2) {
#pragma unroll
        for (int n2 = 0; n2 < 2; ++n2) {
            int n = wv * 32 + n2 * 16 + (l & 15);
#pragma unroll
            for (int r = 0; r < 4; ++r) {
                int m = m0 + m2 * 16 + (l >> 4) * 4 + r;
                z_part[((size_t)s * B_TOT + m) * NOUT + n] = acc[m2][n2][r];
            }
        }
    }
}

// ---------------------------------------------------------------------------
// Kernel 3: reduce 11 split-K partials, add bias, softplus on second half.
// float4 per thread (o-groups never straddle the 64 boundary).
// ---------------------------------------------------------------------------
__global__ __launch_bounds__(256) void k_final(const float* __restrict__ z_part,
                                               const float* __restrict__ b_out,
                                               float* __restrict__ out)
{
    int idx = blockIdx.x * 256 + threadIdx.x;   // 65536 threads, 4 outputs each
    int b  = idx >> 5;
    int o4 = (idx & 31) << 2;                   // 0,4,...,124
    float4 z = *(const float4*)(b_out + o4);
#pragma unroll
    for (int s = 0; s < KSPLIT; ++s) {
        const float4 p = *(const float4*)(z_part + ((size_t)s * B_TOT + b) * NOUT + o4);
        z.x += p.x; z.y += p.y; z.z += p.z; z.w += p.w;
    }
    if (o4 < 64) {
        *(float4*)(out + (size_t)b * 64 + o4) = z;
    } else {
        float4 sp;
        sp.x = fmaxf(z.x, 0.f) + log1pf(expf(-fabsf(z.x)));
        sp.y = fmaxf(z.y, 0.f) + log1pf(expf(-fabsf(z.y)));
        sp.z = fmaxf(z.z, 0.f) + log1pf(expf(-fabsf(z.z)));
        sp.w = fmaxf(z.w, 0.f) + log1pf(expf(-fabsf(z.w)));
        *(float4*)(out + 131072 + (size_t)b * 64 + (o4 - 64)) = sp;
    }
}

// ---------------------------------------------------------------------------
extern "C" void kernel_launch(void* const* d_in, const int* in_sizes, int n_in,
                              void* d_out, int out_size, void* d_ws, size_t ws_size,
                              hipStream_t stream)
{
    const float* x     = (const float*)d_in[0];
    const float* w1    = (const float*)d_in[2];
    const float* b1    = (const float*)d_in[3];
    const float* w2    = (const float*)d_in[4];
    const float* b2    = (const float*)d_in[5];
    const float* w3    = (const float*)d_in[6];
    const float* b3    = (const float*)d_in[7];
    const float* w_out = (const float*)d_in[8];
    const float* b_out = (const float*)d_in[9];
    float* out = (float*)d_out;

    // float-unit offsets: N f16 elements occupy N/2 float units.
    float* ws    = (float*)d_ws;
    f16*   sigh  = (f16*)ws;                        // 2048*8448 f16 = 8,650,752 fu
    f16*   wh    = (f16*)(ws + 8650752);            // 128*8448 f16  =   540,672 fu
    f16*   wA    = (f16*)(ws + 9191424);            // 10,240 f16    =     5,120 fu
    float* zpart = ws + 9196544;                    // 11*2048*128   = 2,883,584 f
    // total 12,080,128 floats ~= 48.3 MB

    hipLaunchKernelGGL(k_prep,   dim3(1),    dim3(256), 0, stream, w1, wA);
    hipLaunchKernelGGL(k_augsig, dim3(544),  dim3(256), 0, stream,
                       x, wA, b1, w2, b2, w3, b3, w_out, wh, sigh);
    hipLaunchKernelGGL(k_gemm,   dim3(704),  dim3(256), 0, stream, sigh, wh, zpart);
    hipLaunchKernelGGL(k_final,  dim3(256),  dim3(256), 0, stream, zpart, b_out, out);
}